// Round 1
// baseline (232.121 us; speedup 1.0000x reference)
//
#include <hip/hip_runtime.h>
#include <stdint.h>

#define DEVI __device__ __forceinline__
typedef unsigned short u16;
typedef __attribute__((ext_vector_type(8))) short s16x8;
typedef __attribute__((ext_vector_type(4))) float f32x4;

typedef __attribute__((address_space(1))) void as1_void;
typedef __attribute__((address_space(3))) void as3_void;

DEVI u16 f2b(float f){
  union { float f; uint32_t u; } x; x.f = f;
  return (u16)((x.u + 0x7fffu + ((x.u >> 16) & 1u)) >> 16);
}

DEVI void gload16(const void* g, void* l){
  __builtin_amdgcn_global_load_lds((as1_void*)g, (as3_void*)l, 16, 0, 0);
}

DEVI f32x4 MFMA(s16x8 a, s16x8 b, f32x4 c){
  return __builtin_amdgcn_mfma_f32_16x16x32_bf16(a, b, c, 0, 0, 0);
}

// ---------------- K0a: fp32 -> bf16 convert (4 elems/thread, exact cover) ----
__global__ void k_cvt(const float* __restrict__ s, u16* __restrict__ d){
  int i = (blockIdx.x * 256 + threadIdx.x) * 4;
  float4 v = *(const float4*)(s + i);
  ushort4 o;
  o.x = f2b(v.x); o.y = f2b(v.y); o.z = f2b(v.z); o.w = f2b(v.w);
  *(ushort4*)(d + i) = o;
}

// ---------------- K0b: [R][C] fp32 -> [C][R] bf16 transpose (per-head via z) -
__global__ void k_tr(const float* __restrict__ src, u16* __restrict__ dst,
                     int R, int C, long sStride, long dStride){
  __shared__ float t[32][33];
  src += (size_t)blockIdx.z * sStride;
  dst += (size_t)blockIdx.z * dStride;
  int c0 = blockIdx.x * 32, r0 = blockIdx.y * 32;
  int tx = threadIdx.x & 31, ty = threadIdx.x >> 5;  // 256 thr: ty 0..7
  #pragma unroll
  for(int i = 0; i < 32; i += 8)
    t[ty + i][tx] = src[(size_t)(r0 + ty + i) * C + c0 + tx];
  __syncthreads();
  #pragma unroll
  for(int i = 0; i < 32; i += 8)
    dst[(size_t)(c0 + ty + i) * R + r0 + tx] = f2b(t[tx][ty + i]);
}

// ---------------- K1/K3: C = A @ Bt^T  (A[M][1024], Bt[N][1024], bf16) -------
// MODE 0: bf16 out [M][1024], bias[col]   (q,k projections)
// MODE 1: bf16 out at ((col>>10)<<20)+(row<<10)+(col&1023), bias[row] (vT)
// MODE 2: fp32 out [M][1024], bias[col]   (final output)
template<int MODE>
__global__ __launch_bounds__(256)
void k_gemm(const u16* __restrict__ A, const u16* __restrict__ Bt,
            const float* __restrict__ bias, void* __restrict__ Cp){
  __shared__ u16 sA[2][128 * 64];
  __shared__ u16 sB[2][128 * 64];
  const int tid = threadIdx.x, w = tid >> 6, l = tid & 63;
  const int m0 = blockIdx.y * 128, n0 = blockIdx.x * 128;
  const int wr = w >> 1, wc = w & 1;
  f32x4 acc[4][4];
  #pragma unroll
  for(int a = 0; a < 4; a++)
    #pragma unroll
    for(int b = 0; b < 4; b++) acc[a][b] = (f32x4){0.f, 0.f, 0.f, 0.f};

  const int NT = 16;  // K = 1024, BK = 64
  auto STAGE = [&](int buf, int t){
    #pragma unroll
    for(int s2 = 0; s2 < 4; s2++){
      int s = 4 * w + s2;
      int r = s * 8 + (l >> 3);
      int ch = (l & 7) ^ (r & 7);
      gload16((const char*)A + ((size_t)(m0 + r) * 1024 + t * 64) * 2 + ch * 16,
              (char*)&sA[buf][0] + s * 1024 + l * 16);
    }
    #pragma unroll
    for(int s2 = 0; s2 < 4; s2++){
      int s = 4 * w + s2;
      int r = s * 8 + (l >> 3);
      int ch = (l & 7) ^ (r & 7);
      gload16((const char*)Bt + ((size_t)(n0 + r) * 1024 + t * 64) * 2 + ch * 16,
              (char*)&sB[buf][0] + s * 1024 + l * 16);
    }
  };
  STAGE(0, 0);
  __syncthreads();
  for(int t = 0; t < NT; t++){
    const int cur = t & 1;
    if(t + 1 < NT) STAGE(cur ^ 1, t + 1);
    const char* pa = (const char*)&sA[cur][0];
    const char* pb = (const char*)&sB[cur][0];
    s16x8 af[4][2], bf[4][2];
    #pragma unroll
    for(int mi = 0; mi < 4; mi++){
      int r = 64 * wr + 16 * mi + (l & 15);
      #pragma unroll
      for(int kk = 0; kk < 2; kk++)
        af[mi][kk] = *(const s16x8*)(pa + r * 128 + ((kk * 64 + 16 * (l >> 4)) ^ ((r & 7) << 4)));
    }
    #pragma unroll
    for(int ni = 0; ni < 4; ni++){
      int r = 64 * wc + 16 * ni + (l & 15);
      #pragma unroll
      for(int kk = 0; kk < 2; kk++)
        bf[ni][kk] = *(const s16x8*)(pb + r * 128 + ((kk * 64 + 16 * (l >> 4)) ^ ((r & 7) << 4)));
    }
    #pragma unroll
    for(int kk = 0; kk < 2; kk++)
      #pragma unroll
      for(int mi = 0; mi < 4; mi++)
        #pragma unroll
        for(int ni = 0; ni < 4; ni++)
          acc[mi][ni] = MFMA(af[mi][kk], bf[ni][kk], acc[mi][ni]);
    __syncthreads();
  }
  #pragma unroll
  for(int mi = 0; mi < 4; mi++){
    #pragma unroll
    for(int ni = 0; ni < 4; ni++){
      #pragma unroll
      for(int i = 0; i < 4; i++){
        int gr = m0 + 64 * wr + 16 * mi + 4 * (l >> 4) + i;
        int gc = n0 + 64 * wc + 16 * ni + (l & 15);
        float v = acc[mi][ni][i];
        if(MODE == 0){
          ((u16*)Cp)[(size_t)gr * 1024 + gc] = f2b(v + bias[gc]);
        } else if(MODE == 1){
          ((u16*)Cp)[((size_t)(gc >> 10) << 20) + ((size_t)gr << 10) + (gc & 1023)] =
              f2b(v + bias[gr]);
        } else {
          ((float*)Cp)[(size_t)gr * 1024 + gc] = v + bias[gc];
        }
      }
    }
  }
}

// ---------------- K2: fused attention per (b,h,64-row q block) ---------------
// q,k in ws as [4096][1024] bf16 (cols h*64+e); vT as [b][h*64+e][1024] bf16.
// Pass A: row sums of exp(S/8). Pass B: recompute S, write normalized attn
// (fp32) + P->bf16->LDS, accumulate PV. Epilogue: concat[b][q][h*64+e] bf16.
__global__ __launch_bounds__(256)
void k_attn(const u16* __restrict__ qws, const u16* __restrict__ kws,
            const u16* __restrict__ vws, float* __restrict__ attn,
            u16* __restrict__ concat){
  __shared__ u16 q_s[64 * 64];
  __shared__ u16 k_s[128 * 64];
  __shared__ u16 v_s[64 * 128];
  __shared__ u16 p_s[64 * 128];
  const int tid = threadIdx.x, w = tid >> 6, l = tid & 63;
  const int bx = blockIdx.x;
  const int qb = bx & 15, bh = bx >> 4, b = bh >> 4, h = bh & 15;
  const char* qg = (const char*)qws + ((size_t)(b * 1024 + qb * 64) * 1024 + h * 64) * 2;
  const char* kg = (const char*)kws + ((size_t)(b * 1024) * 1024 + h * 64) * 2;
  const char* vg = (const char*)vws + ((size_t)b * 1048576 + (size_t)h * 64 * 1024) * 2;
  float* ao = attn + (size_t)((h * 4 + b) * 1024 + qb * 64) * 1024;
  u16* cw = concat + (size_t)(b * 1024 + qb * 64) * 1024 + h * 64;

  // stage q tile [64][64] (swizzled chunks)
  #pragma unroll
  for(int s2 = 0; s2 < 2; s2++){
    int s = 2 * w + s2;
    int r = s * 8 + (l >> 3);
    int ch = (l & 7) ^ (r & 7);
    gload16(qg + (size_t)r * 2048 + ch * 16, (char*)q_s + s * 1024 + l * 16);
  }

  const float KS = 0.18033688011112042f;  // log2(e)/8
  float rs[4] = {0.f, 0.f, 0.f, 0.f};
  s16x8 af0, af1;

  // ---- pass A: denominator sums ----
  for(int kt = 0; kt < 8; kt++){
    __syncthreads();
    #pragma unroll
    for(int s2 = 0; s2 < 4; s2++){
      int s = 4 * w + s2;
      int r = s * 8 + (l >> 3);
      int ch = (l & 7) ^ (r & 7);
      gload16(kg + (size_t)(kt * 128 + r) * 2048 + ch * 16, (char*)k_s + s * 1024 + l * 16);
    }
    __syncthreads();
    if(kt == 0){
      int rq = 16 * w + (l & 15);
      af0 = *(const s16x8*)((const char*)q_s + rq * 128 + ((16 * (l >> 4)) ^ ((rq & 7) << 4)));
      af1 = *(const s16x8*)((const char*)q_s + rq * 128 + ((64 + 16 * (l >> 4)) ^ ((rq & 7) << 4)));
    }
    #pragma unroll
    for(int f = 0; f < 8; f++){
      int r = 16 * f + (l & 15);
      s16x8 b0 = *(const s16x8*)((const char*)k_s + r * 128 + ((16 * (l >> 4)) ^ ((r & 7) << 4)));
      s16x8 b1 = *(const s16x8*)((const char*)k_s + r * 128 + ((64 + 16 * (l >> 4)) ^ ((r & 7) << 4)));
      f32x4 sf = (f32x4){0.f, 0.f, 0.f, 0.f};
      sf = MFMA(af0, b0, sf);
      sf = MFMA(af1, b1, sf);
      #pragma unroll
      for(int i = 0; i < 4; i++) rs[i] += exp2f(sf[i] * KS);
    }
  }
  #pragma unroll
  for(int i = 0; i < 4; i++){
    #pragma unroll
    for(int m = 1; m < 16; m <<= 1) rs[i] += __shfl_xor(rs[i], m, 64);
  }
  float inv[4];
  #pragma unroll
  for(int i = 0; i < 4; i++) inv[i] = 1.0f / rs[i];

  f32x4 oacc[4];
  #pragma unroll
  for(int fe = 0; fe < 4; fe++) oacc[fe] = (f32x4){0.f, 0.f, 0.f, 0.f};

  // ---- pass B: attention write + PV ----
  for(int kt = 0; kt < 8; kt++){
    __syncthreads();
    #pragma unroll
    for(int s2 = 0; s2 < 4; s2++){
      int s = 4 * w + s2;
      int r = s * 8 + (l >> 3);
      int ch = (l & 7) ^ (r & 7);
      gload16(kg + (size_t)(kt * 128 + r) * 2048 + ch * 16, (char*)k_s + s * 1024 + l * 16);
    }
    #pragma unroll
    for(int s2 = 0; s2 < 4; s2++){
      int s = 4 * w + s2;
      int e = s * 4 + (l >> 4);
      int ch = (l & 15) ^ (e & 15);
      gload16(vg + (size_t)e * 2048 + (size_t)kt * 256 + ch * 16, (char*)v_s + s * 1024 + l * 16);
    }
    __syncthreads();
    f32x4 sf[8];
    #pragma unroll
    for(int f = 0; f < 8; f++){
      int r = 16 * f + (l & 15);
      s16x8 b0 = *(const s16x8*)((const char*)k_s + r * 128 + ((16 * (l >> 4)) ^ ((r & 7) << 4)));
      s16x8 b1 = *(const s16x8*)((const char*)k_s + r * 128 + ((64 + 16 * (l >> 4)) ^ ((r & 7) << 4)));
      sf[f] = (f32x4){0.f, 0.f, 0.f, 0.f};
      sf[f] = MFMA(af0, b0, sf[f]);
      sf[f] = MFMA(af1, b1, sf[f]);
    }
    #pragma unroll
    for(int f = 0; f < 8; f++){
      #pragma unroll
      for(int i = 0; i < 4; i++){
        float p = exp2f(sf[f][i] * KS) * inv[i];
        int rr = 16 * w + 4 * (l >> 4) + i;
        ao[(size_t)rr * 1024 + kt * 128 + 16 * f + (l & 15)] = p;
        *(u16*)((char*)p_s + rr * 256 + (((16 * f + (l & 15)) * 2) ^ ((rr & 15) << 4))) = f2b(p);
      }
    }
    __syncthreads();
    #pragma unroll
    for(int kc = 0; kc < 4; kc++){
      int rp = 16 * w + (l & 15);
      s16x8 pa = *(const s16x8*)((const char*)p_s + rp * 256 + ((kc * 64 + 16 * (l >> 4)) ^ ((rp & 15) << 4)));
      #pragma unroll
      for(int fe = 0; fe < 4; fe++){
        int e = 16 * fe + (l & 15);
        s16x8 bv = *(const s16x8*)((const char*)v_s + e * 256 + ((kc * 64 + 16 * (l >> 4)) ^ ((e & 15) << 4)));
        oacc[fe] = MFMA(pa, bv, oacc[fe]);
      }
    }
  }
  #pragma unroll
  for(int fe = 0; fe < 4; fe++){
    #pragma unroll
    for(int i = 0; i < 4; i++){
      int qi = 16 * w + 4 * (l >> 4) + i;
      cw[(size_t)qi * 1024 + 16 * fe + (l & 15)] = f2b(oacc[fe][i]);
    }
  }
}

// ---------------- host launch ------------------------------------------------
extern "C" void kernel_launch(void* const* d_in, const int* in_sizes, int n_in,
                              void* d_out, int out_size, void* d_ws, size_t ws_size,
                              hipStream_t stream){
  const float* Q  = (const float*)d_in[0];
  const float* Kc = (const float*)d_in[1];
  const float* V  = (const float*)d_in[2];
  const float* Wq = (const float*)d_in[3];
  const float* bq = (const float*)d_in[4];
  const float* Wk = (const float*)d_in[5];
  const float* bk = (const float*)d_in[6];
  const float* Wv = (const float*)d_in[7];
  const float* bv = (const float*)d_in[8];
  const float* Wo = (const float*)d_in[9];
  const float* bo = (const float*)d_in[10];
  float* out = (float*)d_out;

  // workspace layout (bytes): needs ~40 MB
  char* ws = (char*)d_ws;
  u16* q_ws      = (u16*)(ws + 0);         // [4096][1024] bf16  8 MB
  u16* k_ws      = (u16*)(ws + 8388608);   // [4096][1024] bf16  8 MB
  u16* vT_ws     = (u16*)(ws + 16777216);  // [b][h*64+e][1024]  8 MB
  u16* concat_ws = (u16*)(ws + 25165824);  // [4096][1024] bf16  8 MB
  u16* WqT = (u16*)(ws + 33554432);        // [1024][1024] bf16  2 MB each
  u16* WkT = (u16*)(ws + 35651584);
  u16* WvT = (u16*)(ws + 37748736);
  u16* WoT = (u16*)(ws + 39845888);

  // scratch bf16 copies of Q/K/V live in the (not yet written) attention
  // region of d_out; they are dead before k_attn overwrites that region.
  u16* Qb = (u16*)((char*)d_out + 16777216);
  u16* Kb = (u16*)((char*)d_out + 25165824);
  u16* Vb = (u16*)((char*)d_out + 33554432);
  float* attn = out + 4194304;

  k_cvt<<<4096, 256, 0, stream>>>(Q,  Qb);
  k_cvt<<<4096, 256, 0, stream>>>(Kc, Kb);
  k_cvt<<<4096, 256, 0, stream>>>(V,  Vb);
  k_tr<<<dim3(2, 32, 16), 256, 0, stream>>>(Wq, WqT, 1024, 64, 65536, 65536);
  k_tr<<<dim3(2, 32, 16), 256, 0, stream>>>(Wk, WkT, 1024, 64, 65536, 65536);
  k_tr<<<dim3(2, 32, 16), 256, 0, stream>>>(Wv, WvT, 1024, 64, 65536, 65536);
  k_tr<<<dim3(32, 32, 1), 256, 0, stream>>>(Wo, WoT, 1024, 1024, 0, 0);

  k_gemm<0><<<dim3(8, 32), 256, 0, stream>>>(Qb, WqT, bq, q_ws);
  k_gemm<0><<<dim3(8, 32), 256, 0, stream>>>(Kb, WkT, bk, k_ws);
  k_gemm<1><<<dim3(32, 8), 256, 0, stream>>>(WvT, Vb, bv, vT_ws);

  k_attn<<<1024, 256, 0, stream>>>(q_ws, k_ws, vT_ws, attn, concat_ws);

  k_gemm<2><<<dim3(8, 32), 256, 0, stream>>>(concat_ws, WoT, bo, out);
}

// Round 2
// 191.482 us; speedup vs baseline: 1.2122x; 1.2122x over previous
//
#include <hip/hip_runtime.h>
#include <stdint.h>

#define DEVI __device__ __forceinline__
typedef unsigned short u16;
typedef __attribute__((ext_vector_type(8))) short s16x8;
typedef __attribute__((ext_vector_type(4))) float f32x4;

typedef __attribute__((address_space(1))) void as1_void;
typedef __attribute__((address_space(3))) void as3_void;

DEVI u16 f2b(float f){
  union { float f; uint32_t u; } x; x.f = f;
  return (u16)((x.u + 0x7fffu + ((x.u >> 16) & 1u)) >> 16);
}

DEVI void gload16(const void* g, void* l){
  __builtin_amdgcn_global_load_lds((as1_void*)g, (as3_void*)l, 16, 0, 0);
}

DEVI f32x4 MFMA(s16x8 a, s16x8 b, f32x4 c){
  return __builtin_amdgcn_mfma_f32_16x16x32_bf16(a, b, c, 0, 0, 0);
}

// ---------------- K0: all prep in ONE launch ---------------------------------
// blocks [0,12288): fp32->bf16 convert of Q,K,V (4096 blocks each)
// blocks [12288,13312): 64x64 transpose tiles for Wq,Wk,Wv (768) + Wo (256)
__global__ __launch_bounds__(256)
void k_prep(const float* __restrict__ Q, const float* __restrict__ Kc,
            const float* __restrict__ V,
            u16* __restrict__ Qb, u16* __restrict__ Kb, u16* __restrict__ Vb,
            const float* __restrict__ Wq, const float* __restrict__ Wk,
            const float* __restrict__ Wv, const float* __restrict__ Wo,
            u16* __restrict__ WqT, u16* __restrict__ WkT,
            u16* __restrict__ WvT, u16* __restrict__ WoT){
  __shared__ float t[64][65];
  const int bid = blockIdx.x, tid = threadIdx.x;
  if(bid < 12288){
    int tno = bid >> 12;     // 0..2
    int blk = bid & 4095;
    const float* s = (tno == 0) ? Q : (tno == 1) ? Kc : V;
    u16* d = (tno == 0) ? Qb : (tno == 1) ? Kb : Vb;
    int i = (blk * 256 + tid) * 4;
    float4 v = *(const float4*)(s + i);
    ushort4 o;
    o.x = f2b(v.x); o.y = f2b(v.y); o.z = f2b(v.z); o.w = f2b(v.w);
    *(ushort4*)(d + i) = o;
  } else {
    int j = bid - 12288;
    const float* src; u16* dst; int C, r0, c0;
    const int R = 1024;
    if(j < 768){
      int tno = j >> 8, rem = j & 255;
      int head = rem >> 4, rt = rem & 15;
      src = ((tno == 0) ? Wq : (tno == 1) ? Wk : Wv) + head * 65536;
      dst = ((tno == 0) ? WqT : (tno == 1) ? WkT : WvT) + head * 65536;
      C = 64; r0 = rt * 64; c0 = 0;
    } else {
      int j2 = j - 768;
      src = Wo; dst = WoT; C = 1024;
      r0 = (j2 & 15) * 64; c0 = (j2 >> 4) * 64;
    }
    int tx = tid & 63, ty = tid >> 6;
    #pragma unroll
    for(int i = 0; i < 64; i += 4)
      t[ty + i][tx] = src[(size_t)(r0 + ty + i) * C + c0 + tx];
    __syncthreads();
    #pragma unroll
    for(int i = 0; i < 64; i += 4)
      dst[(size_t)(c0 + ty + i) * R + r0 + tx] = f2b(t[tx][ty + i]);
  }
}

// ---------------- shared GEMM core: C = A @ Bt^T, K=1024, BN=128, BK=64 ------
// mode 0: bf16 out [M][1024], bias[col]
// mode 1: bf16 out at ((col>>10)<<20)+(row<<10)+(col&1023), bias[row]
// mode 2: fp32 out [M][1024], bias[col]
template<int BM>
DEVI void gemm_core(int mode, const u16* __restrict__ A, const u16* __restrict__ Bt,
                    const float* __restrict__ bias, void* __restrict__ Cp,
                    int m0, int n0, u16* sAb, u16* sBb){
  const int tid = threadIdx.x, w = tid >> 6, l = tid & 63;
  const int wr = w >> 1, wc = w & 1;
  constexpr int MI = BM / 32;   // 16-row fragment tiles per wave (M side)
  f32x4 acc[MI][4];
  #pragma unroll
  for(int a = 0; a < MI; a++)
    #pragma unroll
    for(int b = 0; b < 4; b++) acc[a][b] = (f32x4){0.f, 0.f, 0.f, 0.f};

  const int NT = 16;  // K = 1024 / BK = 64
  auto STAGE = [&](int buf, int t){
    #pragma unroll
    for(int s2 = 0; s2 < BM / 32; s2++){
      int s = (BM / 32) * w + s2;
      int r = s * 8 + (l >> 3);
      int ch = (l & 7) ^ (r & 7);
      gload16((const char*)A + ((size_t)(m0 + r) * 1024 + t * 64) * 2 + ch * 16,
              (char*)(sAb + (size_t)buf * BM * 64) + s * 1024 + l * 16);
    }
    #pragma unroll
    for(int s2 = 0; s2 < 4; s2++){
      int s = 4 * w + s2;
      int r = s * 8 + (l >> 3);
      int ch = (l & 7) ^ (r & 7);
      gload16((const char*)Bt + ((size_t)(n0 + r) * 1024 + t * 64) * 2 + ch * 16,
              (char*)(sBb + (size_t)buf * 8192) + s * 1024 + l * 16);
    }
  };
  STAGE(0, 0);
  __syncthreads();
  for(int t = 0; t < NT; t++){
    const int cur = t & 1;
    if(t + 1 < NT) STAGE(cur ^ 1, t + 1);
    const char* pa = (const char*)(sAb + (size_t)cur * BM * 64);
    const char* pb = (const char*)(sBb + (size_t)cur * 8192);
    s16x8 af[MI][2], bf[4][2];
    #pragma unroll
    for(int mi = 0; mi < MI; mi++){
      int r = (BM / 2) * wr + 16 * mi + (l & 15);
      #pragma unroll
      for(int kk = 0; kk < 2; kk++)
        af[mi][kk] = *(const s16x8*)(pa + r * 128 + ((kk * 64 + 16 * (l >> 4)) ^ ((r & 7) << 4)));
    }
    #pragma unroll
    for(int ni = 0; ni < 4; ni++){
      int r = 64 * wc + 16 * ni + (l & 15);
      #pragma unroll
      for(int kk = 0; kk < 2; kk++)
        bf[ni][kk] = *(const s16x8*)(pb + r * 128 + ((kk * 64 + 16 * (l >> 4)) ^ ((r & 7) << 4)));
    }
    #pragma unroll
    for(int kk = 0; kk < 2; kk++)
      #pragma unroll
      for(int mi = 0; mi < MI; mi++)
        #pragma unroll
        for(int ni = 0; ni < 4; ni++)
          acc[mi][ni] = MFMA(af[mi][kk], bf[ni][kk], acc[mi][ni]);
    __syncthreads();
  }
  #pragma unroll
  for(int mi = 0; mi < MI; mi++){
    #pragma unroll
    for(int ni = 0; ni < 4; ni++){
      #pragma unroll
      for(int i = 0; i < 4; i++){
        int gr = m0 + (BM / 2) * wr + 16 * mi + 4 * (l >> 4) + i;
        int gc = n0 + 64 * wc + 16 * ni + (l & 15);
        float v = acc[mi][ni][i];
        if(mode == 0){
          ((u16*)Cp)[(size_t)gr * 1024 + gc] = f2b(v + bias[gc]);
        } else if(mode == 1){
          ((u16*)Cp)[((size_t)(gc >> 10) << 20) + ((size_t)gr << 10) + (gc & 1023)] =
              f2b(v + bias[gr]);
        } else {
          ((float*)Cp)[(size_t)gr * 1024 + gc] = v + bias[gc];
        }
      }
    }
  }
}

// ---------------- K1: all three projections in ONE launch (768 blocks) -------
__global__ __launch_bounds__(256)
void k_proj(const u16* __restrict__ Qb, const u16* __restrict__ Kb,
            const u16* __restrict__ Vb,
            const u16* __restrict__ WqT, const u16* __restrict__ WkT,
            const u16* __restrict__ WvT,
            const float* __restrict__ bq, const float* __restrict__ bk,
            const float* __restrict__ bv,
            u16* __restrict__ q_ws, u16* __restrict__ k_ws, u16* __restrict__ vT_ws){
  __shared__ u16 sA[2][128 * 64];
  __shared__ u16 sB[2][128 * 64];
  const int bid = blockIdx.x;
  if(bid < 256){        // q: M=4096 (y=bid>>3), N=1024 (x=bid&7)
    gemm_core<128>(0, Qb, WqT, bq, q_ws, (bid >> 3) * 128, (bid & 7) * 128,
                   &sA[0][0], &sB[0][0]);
  } else if(bid < 512){ // k
    int b2 = bid - 256;
    gemm_core<128>(0, Kb, WkT, bk, k_ws, (b2 >> 3) * 128, (b2 & 7) * 128,
                   &sA[0][0], &sB[0][0]);
  } else {              // v^T: A=WvT (M=1024, y=b2>>5), Bt=Vb (N=4096, x=b2&31)
    int b2 = bid - 512;
    gemm_core<128>(1, WvT, Vb, bv, vT_ws, (b2 >> 5) * 128, (b2 & 31) * 128,
                   &sA[0][0], &sB[0][0]);
  }
}

// ---------------- K3: output projection, BM=64 -> 512 blocks, 3/CU -----------
__global__ __launch_bounds__(256)
void k_final(const u16* __restrict__ A, const u16* __restrict__ Bt,
             const float* __restrict__ bias, float* __restrict__ C){
  __shared__ u16 sA[2][64 * 64];
  __shared__ u16 sB[2][128 * 64];
  const int bid = blockIdx.x;   // 512: m0=(bid>>3)*64, n0=(bid&7)*128
  gemm_core<64>(2, A, Bt, bias, C, (bid >> 3) * 64, (bid & 7) * 128,
                &sA[0][0], &sB[0][0]);
}

// ---------------- K2: fused attention per (b,h,64-row q block) ---------------
// XCD-pinned: dispatch index bx -> bh = bx & 63 (so bh mod 8 == XCD), qb = bx>>6.
__global__ __launch_bounds__(256)
void k_attn(const u16* __restrict__ qws, const u16* __restrict__ kws,
            const u16* __restrict__ vws, float* __restrict__ attn,
            u16* __restrict__ concat){
  __shared__ u16 q_s[64 * 64];
  __shared__ u16 k_s[128 * 64];
  __shared__ u16 v_s[64 * 128];
  __shared__ u16 p_s[64 * 128];
  const int tid = threadIdx.x, w = tid >> 6, l = tid & 63;
  const int bx = blockIdx.x;
  const int bh = bx & 63, qb = bx >> 6, b = bh >> 4, h = bh & 15;
  const char* qg = (const char*)qws + ((size_t)(b * 1024 + qb * 64) * 1024 + h * 64) * 2;
  const char* kg = (const char*)kws + ((size_t)(b * 1024) * 1024 + h * 64) * 2;
  const char* vg = (const char*)vws + ((size_t)b * 1048576 + (size_t)h * 64 * 1024) * 2;
  float* ao = attn + (size_t)((h * 4 + b) * 1024 + qb * 64) * 1024;
  u16* cw = concat + (size_t)(b * 1024 + qb * 64) * 1024 + h * 64;

  // stage q tile [64][64] (swizzled chunks)
  #pragma unroll
  for(int s2 = 0; s2 < 2; s2++){
    int s = 2 * w + s2;
    int r = s * 8 + (l >> 3);
    int ch = (l & 7) ^ (r & 7);
    gload16(qg + (size_t)r * 2048 + ch * 16, (char*)q_s + s * 1024 + l * 16);
  }

  const float KS = 0.18033688011112042f;  // log2(e)/8
  float rs[4] = {0.f, 0.f, 0.f, 0.f};
  s16x8 af0, af1;

  // ---- pass A: denominator sums ----
  for(int kt = 0; kt < 8; kt++){
    __syncthreads();
    #pragma unroll
    for(int s2 = 0; s2 < 4; s2++){
      int s = 4 * w + s2;
      int r = s * 8 + (l >> 3);
      int ch = (l & 7) ^ (r & 7);
      gload16(kg + (size_t)(kt * 128 + r) * 2048 + ch * 16, (char*)k_s + s * 1024 + l * 16);
    }
    __syncthreads();
    if(kt == 0){
      int rq = 16 * w + (l & 15);
      af0 = *(const s16x8*)((const char*)q_s + rq * 128 + ((16 * (l >> 4)) ^ ((rq & 7) << 4)));
      af1 = *(const s16x8*)((const char*)q_s + rq * 128 + ((64 + 16 * (l >> 4)) ^ ((rq & 7) << 4)));
    }
    #pragma unroll
    for(int f = 0; f < 8; f++){
      int r = 16 * f + (l & 15);
      s16x8 b0 = *(const s16x8*)((const char*)k_s + r * 128 + ((16 * (l >> 4)) ^ ((r & 7) << 4)));
      s16x8 b1 = *(const s16x8*)((const char*)k_s + r * 128 + ((64 + 16 * (l >> 4)) ^ ((r & 7) << 4)));
      f32x4 sf = (f32x4){0.f, 0.f, 0.f, 0.f};
      sf = MFMA(af0, b0, sf);
      sf = MFMA(af1, b1, sf);
      #pragma unroll
      for(int i = 0; i < 4; i++) rs[i] += exp2f(sf[i] * KS);
    }
  }
  #pragma unroll
  for(int i = 0; i < 4; i++){
    #pragma unroll
    for(int m = 1; m < 16; m <<= 1) rs[i] += __shfl_xor(rs[i], m, 64);
  }
  float inv[4];
  #pragma unroll
  for(int i = 0; i < 4; i++) inv[i] = 1.0f / rs[i];

  f32x4 oacc[4];
  #pragma unroll
  for(int fe = 0; fe < 4; fe++) oacc[fe] = (f32x4){0.f, 0.f, 0.f, 0.f};

  // ---- pass B: attention write + PV ----
  for(int kt = 0; kt < 8; kt++){
    __syncthreads();
    #pragma unroll
    for(int s2 = 0; s2 < 4; s2++){
      int s = 4 * w + s2;
      int r = s * 8 + (l >> 3);
      int ch = (l & 7) ^ (r & 7);
      gload16(kg + (size_t)(kt * 128 + r) * 2048 + ch * 16, (char*)k_s + s * 1024 + l * 16);
    }
    #pragma unroll
    for(int s2 = 0; s2 < 4; s2++){
      int s = 4 * w + s2;
      int e = s * 4 + (l >> 4);
      int ch = (l & 15) ^ (e & 15);
      gload16(vg + (size_t)e * 2048 + (size_t)kt * 256 + ch * 16, (char*)v_s + s * 1024 + l * 16);
    }
    __syncthreads();
    f32x4 sf[8];
    #pragma unroll
    for(int f = 0; f < 8; f++){
      int r = 16 * f + (l & 15);
      s16x8 b0 = *(const s16x8*)((const char*)k_s + r * 128 + ((16 * (l >> 4)) ^ ((r & 7) << 4)));
      s16x8 b1 = *(const s16x8*)((const char*)k_s + r * 128 + ((64 + 16 * (l >> 4)) ^ ((r & 7) << 4)));
      sf[f] = (f32x4){0.f, 0.f, 0.f, 0.f};
      sf[f] = MFMA(af0, b0, sf[f]);
      sf[f] = MFMA(af1, b1, sf[f]);
    }
    #pragma unroll
    for(int f = 0; f < 8; f++){
      #pragma unroll
      for(int i = 0; i < 4; i++){
        float p = exp2f(sf[f][i] * KS) * inv[i];
        int rr = 16 * w + 4 * (l >> 4) + i;
        ao[(size_t)rr * 1024 + kt * 128 + 16 * f + (l & 15)] = p;
        *(u16*)((char*)p_s + rr * 256 + (((16 * f + (l & 15)) * 2) ^ ((rr & 15) << 4))) = f2b(p);
      }
    }
    __syncthreads();
    #pragma unroll
    for(int kc = 0; kc < 4; kc++){
      int rp = 16 * w + (l & 15);
      s16x8 pa = *(const s16x8*)((const char*)p_s + rp * 256 + ((kc * 64 + 16 * (l >> 4)) ^ ((rp & 15) << 4)));
      #pragma unroll
      for(int fe = 0; fe < 4; fe++){
        int e = 16 * fe + (l & 15);
        s16x8 bv = *(const s16x8*)((const char*)v_s + e * 256 + ((kc * 64 + 16 * (l >> 4)) ^ ((e & 15) << 4)));
        oacc[fe] = MFMA(pa, bv, oacc[fe]);
      }
    }
  }
  #pragma unroll
  for(int fe = 0; fe < 4; fe++){
    #pragma unroll
    for(int i = 0; i < 4; i++){
      int qi = 16 * w + 4 * (l >> 4) + i;
      cw[(size_t)qi * 1024 + 16 * fe + (l & 15)] = f2b(oacc[fe][i]);
    }
  }
}

// ---------------- host launch ------------------------------------------------
extern "C" void kernel_launch(void* const* d_in, const int* in_sizes, int n_in,
                              void* d_out, int out_size, void* d_ws, size_t ws_size,
                              hipStream_t stream){
  const float* Q  = (const float*)d_in[0];
  const float* Kc = (const float*)d_in[1];
  const float* V  = (const float*)d_in[2];
  const float* Wq = (const float*)d_in[3];
  const float* bq = (const float*)d_in[4];
  const float* Wk = (const float*)d_in[5];
  const float* bk = (const float*)d_in[6];
  const float* Wv = (const float*)d_in[7];
  const float* bv = (const float*)d_in[8];
  const float* Wo = (const float*)d_in[9];
  const float* bo = (const float*)d_in[10];
  float* out = (float*)d_out;

  // workspace layout (bytes): ~42 MB
  char* ws = (char*)d_ws;
  u16* q_ws      = (u16*)(ws + 0);         // [4096][1024] bf16  8 MB
  u16* k_ws      = (u16*)(ws + 8388608);   // [4096][1024] bf16  8 MB
  u16* vT_ws     = (u16*)(ws + 16777216);  // [b][h*64+e][1024]  8 MB
  u16* concat_ws = (u16*)(ws + 25165824);  // [4096][1024] bf16  8 MB
  u16* WqT = (u16*)(ws + 33554432);        // [1024][1024] bf16  2 MB each
  u16* WkT = (u16*)(ws + 35651584);
  u16* WvT = (u16*)(ws + 37748736);
  u16* WoT = (u16*)(ws + 39845888);

  // scratch bf16 copies of Q/K/V live in the (not yet written) attention
  // region of d_out; dead before k_attn overwrites that region.
  u16* Qb = (u16*)((char*)d_out + 16777216);
  u16* Kb = (u16*)((char*)d_out + 25165824);
  u16* Vb = (u16*)((char*)d_out + 33554432);
  float* attn = out + 4194304;

  k_prep<<<13312, 256, 0, stream>>>(Q, Kc, V, Qb, Kb, Vb,
                                    Wq, Wk, Wv, Wo, WqT, WkT, WvT, WoT);
  k_proj<<<768, 256, 0, stream>>>(Qb, Kb, Vb, WqT, WkT, WvT, bq, bk, bv,
                                  q_ws, k_ws, vT_ws);
  k_attn<<<1024, 256, 0, stream>>>(q_ws, k_ws, vT_ws, attn, concat_ws);
  k_final<<<512, 256, 0, stream>>>(concat_ws, WoT, bo, out);
}